// Round 1
// baseline (2462.774 us; speedup 1.0000x reference)
//
#include <hip/hip_runtime.h>
#include <hip/hip_bf16.h>
#include <math.h>

// Problem: B=4096 queries, D=256, K=65536 centroids (all f32).
// dists[b,k] = ||c_k||^2 - 2 x_b . c_k ; codes = argmin_k ; out0 = centroids[codes] (4096x256), out1 = codes (4096).
// d_in[0]=xhat (unused, shape only), d_in[1]=x_BD, d_in[2]=centroids.

#define QB 64      // queries per block
#define CB 64      // centroids per subtile
#define KCHUNK 4096
#define NKC 16     // 65536 / KCHUNK
#define KT 32      // k-dim tile
#define DDIM 256

// ---------------- Kernel 1: c_sq[k] = sum_d centroids[k][d]^2 ----------------
__global__ __launch_bounds__(256) void csq_kernel(const float* __restrict__ cent,
                                                  float* __restrict__ c_sq) {
  int gtid = blockIdx.x * 256 + threadIdx.x;
  int c = gtid >> 6;            // one wave (64 lanes) per centroid
  int lane = threadIdx.x & 63;
  const float4* row = (const float4*)(cent + (size_t)c * DDIM);
  float4 v = row[lane];         // 64 lanes x 16B = full 256-float row
  float s = v.x * v.x + v.y * v.y + v.z * v.z + v.w * v.w;
#pragma unroll
  for (int off = 32; off > 0; off >>= 1) s += __shfl_down(s, off, 64);
  if (lane == 0) c_sq[c] = s;
}

// ---------------- Kernel 2: tiled f32 GEMM + running argmin ----------------
// Grid: (4096/QB, NKC). Each block: QB queries x KCHUNK centroids.
__global__ __launch_bounds__(256) void dist_argmin_kernel(
    const float* __restrict__ x, const float* __restrict__ cent,
    const float* __restrict__ c_sq,
    float* __restrict__ part_d, int* __restrict__ part_i) {
  __shared__ float As[KT][QB];   // k-major: broadcast-friendly reads
  __shared__ float Bs[KT][CB];
  __shared__ float rd[QB][16];
  __shared__ int   ri[QB][16];

  const int qb = blockIdx.x;     // 0..63
  const int kc = blockIdx.y;     // 0..15
  const int tid = (int)threadIdx.x;
  const int tx = tid & 15;       // centroid micro-tile
  const int ty = tid >> 4;       // query micro-tile
  const int tx4 = tx * 4, ty4 = ty * 4;
  const int lrow = tid >> 3;     // 0..31  (staging: row)
  const int lf4  = tid & 7;      // 0..7   (staging: float4 within KT)

  float bestd[4];
  int   besti[4];
#pragma unroll
  for (int i = 0; i < 4; ++i) { bestd[i] = INFINITY; besti[i] = 0; }

  const float* xbase = x + (size_t)qb * QB * DDIM;

  for (int ct = 0; ct < KCHUNK / CB; ++ct) {
    const int cbase = kc * KCHUNK + ct * CB;
    float acc[4][4] = {};
    for (int k0 = 0; k0 < DDIM; k0 += KT) {
      __syncthreads();  // protect previous tile's readers
#pragma unroll
      for (int r = 0; r < 2; ++r) {
        int row = lrow + r * 32;
        float4 a = *(const float4*)(xbase + (size_t)row * DDIM + k0 + lf4 * 4);
        As[lf4 * 4 + 0][row] = a.x;
        As[lf4 * 4 + 1][row] = a.y;
        As[lf4 * 4 + 2][row] = a.z;
        As[lf4 * 4 + 3][row] = a.w;
        float4 b = *(const float4*)(cent + (size_t)(cbase + row) * DDIM + k0 + lf4 * 4);
        Bs[lf4 * 4 + 0][row] = b.x;
        Bs[lf4 * 4 + 1][row] = b.y;
        Bs[lf4 * 4 + 2][row] = b.z;
        Bs[lf4 * 4 + 3][row] = b.w;
      }
      __syncthreads();
#pragma unroll
      for (int kk = 0; kk < KT; ++kk) {
        float4 av = *(const float4*)&As[kk][ty4];  // 4-addr broadcast, conflict-free
        float4 bv = *(const float4*)&Bs[kk][tx4];  // 2-way (free)
        float a[4] = {av.x, av.y, av.z, av.w};
        float b[4] = {bv.x, bv.y, bv.z, bv.w};
#pragma unroll
        for (int i = 0; i < 4; ++i)
#pragma unroll
          for (int j = 0; j < 4; ++j)
            acc[i][j] = fmaf(a[i], b[j], acc[i][j]);
      }
    }
    // fold 4x4 distances into running per-query argmin (tie -> lowest index)
#pragma unroll
    for (int j = 0; j < 4; ++j) {
      int c = cbase + tx4 + j;
      float cs = c_sq[c];
#pragma unroll
      for (int i = 0; i < 4; ++i) {
        float dd = fmaf(-2.0f, acc[i][j], cs);   // cs - 2*dot (exact *2)
        if (dd < bestd[i] || (dd == bestd[i] && c < besti[i])) {
          bestd[i] = dd; besti[i] = c;
        }
      }
    }
  }

  // cross-thread (tx) reduction per query row
#pragma unroll
  for (int i = 0; i < 4; ++i) { rd[ty4 + i][tx] = bestd[i]; ri[ty4 + i][tx] = besti[i]; }
  __syncthreads();
  if (tid < QB) {
    float bd = rd[tid][0]; int bi = ri[tid][0];
#pragma unroll
    for (int t = 1; t < 16; ++t) {
      float dd = rd[tid][t]; int ii = ri[tid][t];
      if (dd < bd || (dd == bd && ii < bi)) { bd = dd; bi = ii; }
    }
    int q = qb * QB + tid;
    part_d[(size_t)q * NKC + kc] = bd;
    part_i[(size_t)q * NKC + kc] = bi;
  }
}

// ---------------- Kernel 3: combine partials, gather winner row ----------------
__global__ __launch_bounds__(256) void finalize_kernel(
    const float* __restrict__ part_d, const int* __restrict__ part_i,
    const float* __restrict__ cent, float* __restrict__ out) {
  int q = blockIdx.x * 4 + ((int)threadIdx.x >> 6);  // one wave per query
  int lane = (int)threadIdx.x & 63;
  float d = INFINITY; int idx = 0x7fffffff;
  if (lane < NKC) { d = part_d[(size_t)q * NKC + lane]; idx = part_i[(size_t)q * NKC + lane]; }
#pragma unroll
  for (int off = 8; off > 0; off >>= 1) {
    float od = __shfl_down(d, off, 64);
    int   oi = __shfl_down(idx, off, 64);
    if (od < d || (od == d && oi < idx)) { d = od; idx = oi; }
  }
  idx = __shfl(idx, 0, 64);
  float4 v = *(const float4*)(cent + (size_t)idx * DDIM + lane * 4);
  *(float4*)(out + (size_t)q * DDIM + lane * 4) = v;
  if (lane == 0) out[(size_t)4096 * DDIM + q] = (float)idx;  // codes as f32 values
}

extern "C" void kernel_launch(void* const* d_in, const int* in_sizes, int n_in,
                              void* d_out, int out_size, void* d_ws, size_t ws_size,
                              hipStream_t stream) {
  const float* x    = (const float*)d_in[1];   // [4096,256]
  const float* cent = (const float*)d_in[2];   // [65536,256]
  float* out = (float*)d_out;

  float* ws     = (float*)d_ws;
  float* c_sq   = ws;                       // 65536 f32
  float* part_d = ws + 65536;               // 4096*16 f32
  int*   part_i = (int*)(ws + 65536 + 4096 * NKC);  // 4096*16 i32

  csq_kernel<<<(65536 * 64) / 256, 256, 0, stream>>>(cent, c_sq);
  dist_argmin_kernel<<<dim3(4096 / QB, NKC), 256, 0, stream>>>(x, cent, c_sq, part_d, part_i);
  finalize_kernel<<<4096 / 4, 256, 0, stream>>>(part_d, part_i, cent, out);
}

// Round 2
// 710.920 us; speedup vs baseline: 3.4642x; 3.4642x over previous
//
#include <hip/hip_runtime.h>
#include <hip/hip_bf16.h>
#include <math.h>

// B=4096 queries, D=256, K=65536 centroids (f32).
// dists[b,k] = ||c_k||^2 - 2 x_b.c_k ; codes=argmin ; out0=centroids[codes], out1=codes.
// Strategy: f16x2 split-emulated f32 GEMM on MFMA (3 terms: x0c0 + (x0c1s+x1s c0)/2048),
// per-4096-chunk approx argmin, then exact-f32 rescore of the 16 chunk winners.

#define DDIM 256
#define NKC 16
#define KCHUNK 4096

typedef __attribute__((ext_vector_type(8))) _Float16 half8;
typedef __attribute__((ext_vector_type(4))) _Float16 half4;
typedef __attribute__((ext_vector_type(4))) float f32x4;

__device__ __forceinline__ void gl_lds16(const void* g, void* l) {
  __builtin_amdgcn_global_load_lds((const __attribute__((address_space(1))) void*)g,
                                   (__attribute__((address_space(3))) void*)l, 16, 0, 0);
}

// ---------------- split: f32 -> (h0, h1*2048) f16 pair ----------------
__global__ __launch_bounds__(256) void split_kernel(const float* __restrict__ in,
                                                    _Float16* __restrict__ o0,
                                                    _Float16* __restrict__ o1, int n4) {
  int i = blockIdx.x * 256 + threadIdx.x;
  if (i >= n4) return;
  float4 v = ((const float4*)in)[i];
  float vv[4] = {v.x, v.y, v.z, v.w};
  half4 h0, h1;
#pragma unroll
  for (int e = 0; e < 4; ++e) {
    float x = vv[e];
    // avoid f16 subnormals in the hi part; residual is scaled into normal range
    _Float16 a = (fabsf(x) < 6.103515625e-5f) ? (_Float16)0.f : (_Float16)x;
    float r = (x - (float)a) * 2048.0f;   // exact: conversion + Sterbenz sub + pow2 scale
    h0[e] = a;
    h1[e] = (_Float16)r;
  }
  *(half4*)(o0 + (size_t)i * 4) = h0;
  *(half4*)(o1 + (size_t)i * 4) = h1;
}

// ---------------- c_sq[k] = sum_d centroids[k][d]^2 (exact f32) ----------------
__global__ __launch_bounds__(256) void csq_kernel(const float* __restrict__ cent,
                                                  float* __restrict__ c_sq) {
  int gtid = blockIdx.x * 256 + threadIdx.x;
  int c = gtid >> 6;
  int lane = threadIdx.x & 63;
  const float4* row = (const float4*)(cent + (size_t)c * DDIM);
  float4 v = row[lane];
  float s = v.x * v.x + v.y * v.y + v.z * v.z + v.w * v.w;
#pragma unroll
  for (int off = 32; off > 0; off >>= 1) s += __shfl_down(s, off, 64);
  if (lane == 0) c_sq[c] = s;
}

// ---------------- MFMA distance + per-chunk argmin ----------------
// Grid (32, 16): qb covers 128 queries, kc covers 4096 centroids (32 ct-subtiles of 128).
// LDS tile layout per split: [8 subtiles s][4 quads q][16 rows r][8 f16]  (quad-major:
// frag ds_read_b128 is 2-way-bank (free) AND staging is lane-contiguous for global_load_lds).
__global__ __launch_bounds__(256, 2) void mfma_dist_kernel(
    const _Float16* __restrict__ x0, const _Float16* __restrict__ x1,
    const _Float16* __restrict__ c0, const _Float16* __restrict__ c1,
    const float* __restrict__ c_sq,
    float* __restrict__ part_d, int* __restrict__ part_i) {
  __shared__ __align__(16) _Float16 As0[4096], As1[4096], Bs0[4096], Bs1[4096];
  __shared__ float rd[2][128];
  __shared__ int   ri[2][128];

  const int qb = blockIdx.x, kc = blockIdx.y;
  const int tid = (int)threadIdx.x;
  const int lane = tid & 63, w = tid >> 6;
  const int mh = w >> 1, nh = w & 1;          // wave quadrant: 64x64 of the 128x128 tile
  const int col = lane & 15, quad = lane >> 4;
  const int qrow0 = qb * 128;

  float bestd[4][4];
  int   besti[4][4];
#pragma unroll
  for (int mt = 0; mt < 4; ++mt)
#pragma unroll
    for (int rg = 0; rg < 4; ++rg) { bestd[mt][rg] = INFINITY; besti[mt][rg] = 0x7fffffff; }

  for (int ct = 0; ct < 32; ++ct) {
    const int cbase = kc * KCHUNK + ct * 128;
    f32x4 hi[4][4], lo[4][4];
#pragma unroll
    for (int mt = 0; mt < 4; ++mt)
#pragma unroll
      for (int nt = 0; nt < 4; ++nt) { hi[mt][nt] = (f32x4)0.0f; lo[mt][nt] = (f32x4)0.0f; }

    for (int kt = 0; kt < 8; ++kt) {
      const int k0 = kt * 32;
      __syncthreads();  // previous tile's ds_reads drained (compiler emits full waitcnt)
#pragma unroll
      for (int i = 0; i < 2; ++i) {
        int u = i * 256 + tid;            // 0..511
        int s = u >> 6, q = (u >> 4) & 3, r = u & 15;
        size_t arow = (size_t)(qrow0 + s * 16 + r) * DDIM + k0 + q * 8;
        size_t brow = (size_t)(cbase + s * 16 + r) * DDIM + k0 + q * 8;
        gl_lds16(x0 + arow, As0 + (size_t)u * 8);
        gl_lds16(x1 + arow, As1 + (size_t)u * 8);
        gl_lds16(c0 + brow, Bs0 + (size_t)u * 8);
        gl_lds16(c1 + brow, Bs1 + (size_t)u * 8);
      }
      __syncthreads();

      half8 b0f[4], b1f[4];
#pragma unroll
      for (int nt = 0; nt < 4; ++nt) {
        int off = (((nh * 4 + nt) * 4 + quad) * 16 + col) * 8;
        b0f[nt] = *(const half8*)(Bs0 + off);
        b1f[nt] = *(const half8*)(Bs1 + off);
      }
#pragma unroll
      for (int mt = 0; mt < 4; ++mt) {
        int off = (((mh * 4 + mt) * 4 + quad) * 16 + col) * 8;
        half8 a0f = *(const half8*)(As0 + off);
        half8 a1f = *(const half8*)(As1 + off);
#pragma unroll
        for (int nt = 0; nt < 4; ++nt) {
          hi[mt][nt] = __builtin_amdgcn_mfma_f32_16x16x32_f16(a0f, b0f[nt], hi[mt][nt], 0, 0, 0);
          lo[mt][nt] = __builtin_amdgcn_mfma_f32_16x16x32_f16(a0f, b1f[nt], lo[mt][nt], 0, 0, 0);
          lo[mt][nt] = __builtin_amdgcn_mfma_f32_16x16x32_f16(a1f, b0f[nt], lo[mt][nt], 0, 0, 0);
        }
      }
    }
    // fold 128-wide chunk into running per-row argmin (C layout: row=quad*4+rg, col=lane&15)
#pragma unroll
    for (int nt = 0; nt < 4; ++nt) {
      int cidx = cbase + nh * 64 + nt * 16 + col;
      float cs = c_sq[cidx];
#pragma unroll
      for (int mt = 0; mt < 4; ++mt)
#pragma unroll
        for (int rg = 0; rg < 4; ++rg) {
          float dot = hi[mt][nt][rg] + lo[mt][nt][rg] * (1.0f / 2048.0f);
          float d = fmaf(-2.0f, dot, cs);
          if (d < bestd[mt][rg] || (d == bestd[mt][rg] && cidx < besti[mt][rg])) {
            bestd[mt][rg] = d; besti[mt][rg] = cidx;
          }
        }
    }
  }

  // reduce across the 16 col-lanes holding each row
#pragma unroll
  for (int mt = 0; mt < 4; ++mt)
#pragma unroll
    for (int rg = 0; rg < 4; ++rg) {
      float d = bestd[mt][rg]; int ix = besti[mt][rg];
#pragma unroll
      for (int off = 1; off < 16; off <<= 1) {
        float od = __shfl_xor(d, off, 64);
        int   oi = __shfl_xor(ix, off, 64);
        if (od < d || (od == d && oi < ix)) { d = od; ix = oi; }
      }
      if (col == 0) {
        int row = mh * 64 + mt * 16 + quad * 4 + rg;
        rd[nh][row] = d; ri[nh][row] = ix;
      }
    }
  __syncthreads();
  if (tid < 128) {
    float d0 = rd[0][tid]; int i0 = ri[0][tid];
    float d1 = rd[1][tid]; int i1 = ri[1][tid];
    if (d1 < d0 || (d1 == d0 && i1 < i0)) { d0 = d1; i0 = i1; }
    int qg = qrow0 + tid;
    part_d[(size_t)qg * NKC + kc] = d0;
    part_i[(size_t)qg * NKC + kc] = i0;
  }
}

// ---------------- fallback exact-f32 VALU kernel (round-1), used if ws too small ----------
__global__ __launch_bounds__(256) void dist_argmin_kernel(
    const float* __restrict__ x, const float* __restrict__ cent,
    const float* __restrict__ c_sq,
    float* __restrict__ part_d, int* __restrict__ part_i) {
  __shared__ float As[32][64];
  __shared__ float Bs[32][64];
  __shared__ float rdl[64][16];
  __shared__ int   ril[64][16];
  const int qb = blockIdx.x, kc = blockIdx.y;
  const int tid = (int)threadIdx.x;
  const int tx = tid & 15, ty = tid >> 4;
  const int tx4 = tx * 4, ty4 = ty * 4;
  const int lrow = tid >> 3, lf4 = tid & 7;
  float bd[4]; int bi[4];
#pragma unroll
  for (int i = 0; i < 4; ++i) { bd[i] = INFINITY; bi[i] = 0; }
  const float* xbase = x + (size_t)qb * 64 * DDIM;
  for (int ct = 0; ct < KCHUNK / 64; ++ct) {
    const int cbase = kc * KCHUNK + ct * 64;
    float acc[4][4] = {};
    for (int k0 = 0; k0 < DDIM; k0 += 32) {
      __syncthreads();
#pragma unroll
      for (int r = 0; r < 2; ++r) {
        int row = lrow + r * 32;
        float4 a = *(const float4*)(xbase + (size_t)row * DDIM + k0 + lf4 * 4);
        As[lf4 * 4 + 0][row] = a.x; As[lf4 * 4 + 1][row] = a.y;
        As[lf4 * 4 + 2][row] = a.z; As[lf4 * 4 + 3][row] = a.w;
        float4 b = *(const float4*)(cent + (size_t)(cbase + row) * DDIM + k0 + lf4 * 4);
        Bs[lf4 * 4 + 0][row] = b.x; Bs[lf4 * 4 + 1][row] = b.y;
        Bs[lf4 * 4 + 2][row] = b.z; Bs[lf4 * 4 + 3][row] = b.w;
      }
      __syncthreads();
#pragma unroll
      for (int kk = 0; kk < 32; ++kk) {
        float4 av = *(const float4*)&As[kk][ty4];
        float4 bv = *(const float4*)&Bs[kk][tx4];
        float a[4] = {av.x, av.y, av.z, av.w};
        float b[4] = {bv.x, bv.y, bv.z, bv.w};
#pragma unroll
        for (int i = 0; i < 4; ++i)
#pragma unroll
          for (int j = 0; j < 4; ++j) acc[i][j] = fmaf(a[i], b[j], acc[i][j]);
      }
    }
#pragma unroll
    for (int j = 0; j < 4; ++j) {
      int c = cbase + tx4 + j;
      float cs = c_sq[c];
#pragma unroll
      for (int i = 0; i < 4; ++i) {
        float dd = fmaf(-2.0f, acc[i][j], cs);
        if (dd < bd[i] || (dd == bd[i] && c < bi[i])) { bd[i] = dd; bi[i] = c; }
      }
    }
  }
#pragma unroll
  for (int i = 0; i < 4; ++i) { rdl[ty4 + i][tx] = bd[i]; ril[ty4 + i][tx] = bi[i]; }
  __syncthreads();
  if (tid < 64) {
    float d0 = rdl[tid][0]; int i0 = ril[tid][0];
#pragma unroll
    for (int t = 1; t < 16; ++t) {
      float dd = rdl[tid][t]; int ii = ril[tid][t];
      if (dd < d0 || (dd == d0 && ii < i0)) { d0 = dd; i0 = ii; }
    }
    int q = qb * 64 + tid;
    part_d[(size_t)q * NKC + kc] = d0;
    part_i[(size_t)q * NKC + kc] = i0;
  }
}

// ---------------- finalize: exact-f32 rescore of 16 chunk winners + gather ----------------
__global__ __launch_bounds__(256) void finalize_rescore(
    const int* __restrict__ part_i, const float* __restrict__ x,
    const float* __restrict__ cent, const float* __restrict__ c_sq,
    float* __restrict__ out) {
  int q = blockIdx.x * 4 + ((int)threadIdx.x >> 6);
  int lane = (int)threadIdx.x & 63;
  float4 xv = ((const float4*)x)[(size_t)q * 64 + lane];
  float bd = INFINITY; int bi = 0x7fffffff;
  for (int p = 0; p < NKC; ++p) {
    int idx = part_i[(size_t)q * NKC + p];
    float4 cv = ((const float4*)cent)[(size_t)idx * 64 + lane];
    float s = xv.x * cv.x + xv.y * cv.y + xv.z * cv.z + xv.w * cv.w;
#pragma unroll
    for (int off = 32; off > 0; off >>= 1) s += __shfl_down(s, off, 64);
    s = __shfl(s, 0, 64);
    float d = fmaf(-2.0f, s, c_sq[idx]);
    if (d < bd || (d == bd && idx < bi)) { bd = d; bi = idx; }
  }
  float4 v = ((const float4*)cent)[(size_t)bi * 64 + lane];
  ((float4*)out)[(size_t)q * 64 + lane] = v;
  if (lane == 0) out[(size_t)4096 * DDIM + q] = (float)bi;
}

extern "C" void kernel_launch(void* const* d_in, const int* in_sizes, int n_in,
                              void* d_out, int out_size, void* d_ws, size_t ws_size,
                              hipStream_t stream) {
  const float* x    = (const float*)d_in[1];   // [4096,256]
  const float* cent = (const float*)d_in[2];   // [65536,256]
  float* out = (float*)d_out;
  char* ws = (char*)d_ws;

  const size_t OFF_C0  = 0;
  const size_t OFF_C1  = 33554432;
  const size_t OFF_X0  = 67108864;
  const size_t OFF_X1  = 69206016;
  const size_t OFF_CSQ = 71303168;
  const size_t OFF_PD  = 71565312;
  const size_t OFF_PI  = 71827456;
  const size_t NEED    = 72089600;

  if (ws_size >= NEED) {
    _Float16* c0 = (_Float16*)(ws + OFF_C0);
    _Float16* c1 = (_Float16*)(ws + OFF_C1);
    _Float16* x0 = (_Float16*)(ws + OFF_X0);
    _Float16* x1 = (_Float16*)(ws + OFF_X1);
    float* c_sq   = (float*)(ws + OFF_CSQ);
    float* part_d = (float*)(ws + OFF_PD);
    int*   part_i = (int*)(ws + OFF_PI);

    split_kernel<<<16384, 256, 0, stream>>>(cent, c0, c1, 65536 * 256 / 4);
    split_kernel<<<1024, 256, 0, stream>>>(x, x0, x1, 4096 * 256 / 4);
    csq_kernel<<<16384, 256, 0, stream>>>(cent, c_sq);
    mfma_dist_kernel<<<dim3(32, 16), 256, 0, stream>>>(x0, x1, c0, c1, c_sq, part_d, part_i);
    finalize_rescore<<<1024, 256, 0, stream>>>(part_i, x, cent, c_sq, out);
  } else {
    float* c_sq   = (float*)ws;
    float* part_d = (float*)(ws + 65536 * 4);
    int*   part_i = (int*)(ws + 65536 * 4 + 65536 * 4);
    csq_kernel<<<16384, 256, 0, stream>>>(cent, c_sq);
    dist_argmin_kernel<<<dim3(64, 16), 256, 0, stream>>>(x, cent, c_sq, part_d, part_i);
    finalize_rescore<<<1024, 256, 0, stream>>>(part_i, x, cent, c_sq, out);
  }
}